// Round 4
// baseline (408.393 us; speedup 1.0000x reference)
//
#include <hip/hip_runtime.h>

#define CC 128          // channels
#define BSEG 16         // segments
#define GRP 4           // segments per group (4 x ~32MB = ~128MB, fits 256MB L3)
#define NGRP (BSEG / GRP)
#define EPSV 1e-5f

// Native clang vector (valid for __builtin_nontemporal_store, unlike HIP float4).
typedef float v4f __attribute__((ext_vector_type(4)));

// first index i in [0,n) with a[i] >= v   (a sorted ascending)
__device__ __forceinline__ int lower_bound_dev(const int* __restrict__ a, int n, int v)
{
    int lo = 0, hi = n;
    while (lo < hi) {
        const int mid = (lo + hi) >> 1;
        if (a[mid] < v) lo = mid + 1; else hi = mid;
    }
    return lo;
}

// ---------------------------------------------------------------------------
// Stats for group g (segments [4g, 4g+4)): per-segment per-channel sum/sumsq.
// Segment boundaries come from binary search (batch_idx is sorted), so the
// main loop does ZERO bidx loads: local segment id = 3 register compares.
// Each block owns a contiguous chunk of the group's rows; uniform chunks
// (common) use an LDS cross-lane reduce + 256 atomics; chunks straddling a
// boundary (<= 3 per group) use a flush-on-change path.
// ---------------------------------------------------------------------------
__global__ __launch_bounds__(256) void ms_stats_g(const float* __restrict__ x,
                                                  const int* __restrict__ bidx, int n,
                                                  float* __restrict__ sum,
                                                  float* __restrict__ sumsq,
                                                  int g)
{
    __shared__ int sb[GRP + 1];
    if (threadIdx.x <= GRP)
        sb[threadIdx.x] = lower_bound_dev(bidx, n, g * GRP + (int)threadIdx.x);
    __syncthreads();
    const int b0 = sb[0], b1 = sb[1], b2 = sb[2], b3 = sb[3], b4 = sb[4];

    const int R = b4 - b0;
    if (R <= 0) return;
    const int chunk = (R + gridDim.x - 1) / gridDim.x;
    const int rs = b0 + blockIdx.x * chunk;
    const int re = min(rs + chunk, b4);
    if (rs >= re) return;

    const int tq = threadIdx.x & 31;   // channel quad 0..31
    const int tr = threadIdx.x >> 5;   // row lane 0..7

    float s0 = 0.f, s1 = 0.f, s2 = 0.f, s3 = 0.f;
    float q0 = 0.f, q1 = 0.f, q2 = 0.f, q3 = 0.f;

    const int segA = (rs >= b1) + (rs >= b2) + (rs >= b3);
    const int segB = ((re - 1) >= b1) + ((re - 1) >= b2) + ((re - 1) >= b3);

    if (segA == segB) {
        // Uniform chunk (block-uniform condition).
        for (int r = rs + tr; r < re; r += 8) {
            const v4f v = *reinterpret_cast<const v4f*>(x + (size_t)r * CC + tq * 4);
            s0 += v.x; s1 += v.y; s2 += v.z; s3 += v.w;
            q0 += v.x * v.x; q1 += v.y * v.y; q2 += v.z * v.z; q3 += v.w * v.w;
        }
        // LDS reduce of 8 row-lanes; layout [tr][slot][tq] is lane-consecutive.
        __shared__ float red[8][8][32];
        red[tr][0][tq] = s0; red[tr][1][tq] = s1; red[tr][2][tq] = s2; red[tr][3][tq] = s3;
        red[tr][4][tq] = q0; red[tr][5][tq] = q1; red[tr][6][tq] = q2; red[tr][7][tq] = q3;
        __syncthreads();
        const int j = threadIdx.x >> 5;   // slot 0..7 (0-3 sum, 4-7 sumsq)
        float acc = 0.f;
        #pragma unroll
        for (int k = 0; k < 8; ++k) acc += red[k][j][tq];
        const int ch = tq * 4 + (j & 3);
        atomicAdd(((j < 4) ? sum : sumsq) + (g * GRP + segA) * CC + ch, acc);
    } else {
        // Boundary chunk (rare): flush per-thread accumulators on segment change.
        int cur = -1;
        for (int r = rs + tr; r < re; r += 8) {
            const int seg = (r >= b1) + (r >= b2) + (r >= b3);
            if (seg != cur) {
                if (cur >= 0) {
                    float* sd = sum   + (g * GRP + cur) * CC + tq * 4;
                    float* qd = sumsq + (g * GRP + cur) * CC + tq * 4;
                    atomicAdd(sd + 0, s0); atomicAdd(sd + 1, s1);
                    atomicAdd(sd + 2, s2); atomicAdd(sd + 3, s3);
                    atomicAdd(qd + 0, q0); atomicAdd(qd + 1, q1);
                    atomicAdd(qd + 2, q2); atomicAdd(qd + 3, q3);
                    s0 = s1 = s2 = s3 = q0 = q1 = q2 = q3 = 0.f;
                }
                cur = seg;
            }
            const v4f v = *reinterpret_cast<const v4f*>(x + (size_t)r * CC + tq * 4);
            s0 += v.x; s1 += v.y; s2 += v.z; s3 += v.w;
            q0 += v.x * v.x; q1 += v.y * v.y; q2 += v.z * v.z; q3 += v.w * v.w;
        }
        if (cur >= 0) {
            float* sd = sum   + (g * GRP + cur) * CC + tq * 4;
            float* qd = sumsq + (g * GRP + cur) * CC + tq * 4;
            atomicAdd(sd + 0, s0); atomicAdd(sd + 1, s1);
            atomicAdd(sd + 2, s2); atomicAdd(sd + 3, s3);
            atomicAdd(qd + 0, q0); atomicAdd(qd + 1, q1);
            atomicAdd(qd + 2, q2); atomicAdd(qd + 3, q3);
        }
    }
}

// ---------------------------------------------------------------------------
// Normalize group g. The group's 128MB of x was just streamed through L3 by
// ms_stats_g -> this re-read is mostly L3 hits. Finalize (mean/var -> 
// scale/shift, counts from boundary diffs) is fused into the LDS preload.
// Output uses nontemporal stores to avoid evicting the group from L3.
// ---------------------------------------------------------------------------
__global__ __launch_bounds__(256) void ms_norm_g(const float* __restrict__ x,
                                                 const int* __restrict__ bidx, int n,
                                                 const float* __restrict__ sum,
                                                 const float* __restrict__ sumsq,
                                                 const float* __restrict__ w,
                                                 const float* __restrict__ bias,
                                                 float* __restrict__ out,
                                                 int g)
{
    __shared__ int sb[GRP + 1];
    __shared__ v4f s_scale[GRP * 32];
    __shared__ v4f s_shift[GRP * 32];
    if (threadIdx.x <= GRP)
        sb[threadIdx.x] = lower_bound_dev(bidx, n, g * GRP + (int)threadIdx.x);
    __syncthreads();

    for (int i = threadIdx.x; i < GRP * CC; i += 256) {
        const int sl = i >> 7;            // local segment 0..3 (CC==128)
        const int c  = i & (CC - 1);
        const float nn   = fmaxf((float)(sb[sl + 1] - sb[sl]), 1.0f);
        const int   gi   = (g * GRP + sl) * CC + c;
        const float mean = sum[gi] / nn;
        const float var  = fmaxf(sumsq[gi] / nn - mean * mean, 0.0f);
        const float sc   = rsqrtf(var + EPSV) * w[c];
        reinterpret_cast<float*>(s_scale)[i] = sc;
        reinterpret_cast<float*>(s_shift)[i] = fmaf(-mean, sc, bias[c]);
    }
    __syncthreads();
    const int b1 = sb[1], b2 = sb[2], b3 = sb[3];

    const unsigned f0 = (unsigned)sb[0] * 32u;   // first float4 index of group
    const unsigned f4 = (unsigned)sb[4] * 32u;   // one past last
    const unsigned stride = gridDim.x * blockDim.x;
    for (unsigned idx = f0 + blockIdx.x * blockDim.x + threadIdx.x; idx < f4; idx += stride) {
        const int r  = (int)(idx >> 5);
        const int q  = (int)(idx & 31);
        const int sl = (r >= b1) + (r >= b2) + (r >= b3);
        const v4f v  = reinterpret_cast<const v4f*>(x)[idx];
        const v4f sc = s_scale[sl * 32 + q];
        const v4f sh = s_shift[sl * 32 + q];
        v4f o;
        o.x = fmaf(v.x, sc.x, sh.x);
        o.y = fmaf(v.y, sc.y, sh.y);
        o.z = fmaf(v.z, sc.z, sh.z);
        o.w = fmaf(v.w, sc.w, sh.w);
        __builtin_nontemporal_store(o, reinterpret_cast<v4f*>(out) + idx);
    }
}

// ---------------------------------------------------------------------------
extern "C" void kernel_launch(void* const* d_in, const int* in_sizes, int n_in,
                              void* d_out, int out_size, void* d_ws, size_t ws_size,
                              hipStream_t stream)
{
    const float* x    = (const float*)d_in[0];
    const int*   bidx = (const int*)d_in[1];
    const float* w    = (const float*)d_in[2];
    const float* bias = (const float*)d_in[3];
    float* out = (float*)d_out;
    const int n = in_sizes[1];   // number of rows (batch_idx length)

    // Workspace layout (floats): sum[B*C] | sumsq[B*C]
    float* ws    = (float*)d_ws;
    float* sum   = ws;
    float* sumsq = ws + BSEG * CC;

    // Zero the accumulators (ws is poisoned; must be replay-safe).
    (void)hipMemsetAsync(d_ws, 0, (size_t)(2 * BSEG * CC) * sizeof(float), stream);

    // Pipeline over segment groups: stats(g) streams ~128MB through L3,
    // norm(g) immediately re-reads it (L3-hot) and writes out nontemporally.
    for (int g = 0; g < NGRP; ++g) {
        ms_stats_g<<<2048, 256, 0, stream>>>(x, bidx, n, sum, sumsq, g);
        ms_norm_g<<<2048, 256, 0, stream>>>(x, bidx, n, sum, sumsq, w, bias, out, g);
    }
}

// Round 5
// 345.167 us; speedup vs baseline: 1.1832x; 1.1832x over previous
//
#include <hip/hip_runtime.h>

#define CC 128          // channels
#define BSEG 16         // segments
#define EPSV 1e-5f
#define ROWS_PER_BLOCK 512
#define NORM_GRID 2048

// Native clang vector (valid for __builtin_nontemporal_store, unlike HIP float4).
typedef float v4f __attribute__((ext_vector_type(4)));

__device__ __forceinline__ v4f vmax0(v4f a)
{
    v4f r; r.x = fmaxf(a.x, 0.f); r.y = fmaxf(a.y, 0.f);
    r.z = fmaxf(a.z, 0.f); r.w = fmaxf(a.w, 0.f); return r;
}
__device__ __forceinline__ v4f vrsqrt_eps(v4f a)
{
    v4f r; r.x = rsqrtf(a.x + EPSV); r.y = rsqrtf(a.y + EPSV);
    r.z = rsqrtf(a.z + EPSV); r.w = rsqrtf(a.w + EPSV); return r;
}

// ---------------------------------------------------------------------------
// Kernel 1: per-segment per-channel sum / sumsq / count.
// Block owns ROWS_PER_BLOCK contiguous rows, FORWARD traversal (leaves the
// tail of x freshest in L3 for the reverse-order normalize pass).
// Thread (tr,tq) = (row-lane 0..7, channel-quad 0..31); inner loop unrolled
// x2 (two independent dwordx4 loads in flight per thread).
// Uniform blocks (common; batch_idx sorted): LDS reduce + 256 atomics.
// Boundary blocks (<=15): flush-on-segment-change atomic path.
// ---------------------------------------------------------------------------
__global__ __launch_bounds__(256) void ms_stats(const float* __restrict__ x,
                                                const int* __restrict__ bidx,
                                                int n,
                                                float* __restrict__ sum,
                                                float* __restrict__ sumsq,
                                                float* __restrict__ cnt)
{
    const int r0 = blockIdx.x * ROWS_PER_BLOCK;
    if (r0 >= n) return;
    const int rend = min(r0 + ROWS_PER_BLOCK, n);
    const int tq = threadIdx.x & 31;   // channel quad 0..31
    const int tr = threadIdx.x >> 5;   // row lane 0..7

    const int seg_first = bidx[r0];
    const int seg_last  = bidx[rend - 1];

    v4f s = {0.f, 0.f, 0.f, 0.f};
    v4f q = {0.f, 0.f, 0.f, 0.f};

    if (seg_first == seg_last) {
        // Uniform block: unrolled x2 for memory-level parallelism.
        int r = r0 + tr;
        for (; r + 8 < rend; r += 16) {
            const v4f a = *reinterpret_cast<const v4f*>(x + (size_t)r * CC + tq * 4);
            const v4f b = *reinterpret_cast<const v4f*>(x + (size_t)(r + 8) * CC + tq * 4);
            s += a; q += a * a;
            s += b; q += b * b;
        }
        if (r < rend) {
            const v4f a = *reinterpret_cast<const v4f*>(x + (size_t)r * CC + tq * 4);
            s += a; q += a * a;
        }
        // LDS reduce of 8 row-lanes; layout [tr][slot][tq] is lane-consecutive.
        __shared__ float red[8][8][32];
        red[tr][0][tq] = s.x; red[tr][1][tq] = s.y; red[tr][2][tq] = s.z; red[tr][3][tq] = s.w;
        red[tr][4][tq] = q.x; red[tr][5][tq] = q.y; red[tr][6][tq] = q.z; red[tr][7][tq] = q.w;
        __syncthreads();
        const int j = threadIdx.x >> 5;   // slot 0..7 (0-3 sum, 4-7 sumsq)
        float acc = 0.f;
        #pragma unroll
        for (int k = 0; k < 8; ++k) acc += red[k][j][tq];
        const int ch = tq * 4 + (j & 3);
        atomicAdd(((j < 4) ? sum : sumsq) + seg_first * CC + ch, acc);
        if (threadIdx.x == 0)
            atomicAdd(cnt + seg_first, (float)(rend - r0));
    } else {
        // Boundary block (rare): flush per-thread accumulators on segment change.
        int cur = -1;
        float rows = 0.f;
        for (int r = r0 + tr; r < rend; r += 8) {
            const int seg = bidx[r];
            if (seg != cur) {
                if (cur >= 0) {
                    float* sd = sum   + cur * CC + tq * 4;
                    float* qd = sumsq + cur * CC + tq * 4;
                    atomicAdd(sd + 0, s.x); atomicAdd(sd + 1, s.y);
                    atomicAdd(sd + 2, s.z); atomicAdd(sd + 3, s.w);
                    atomicAdd(qd + 0, q.x); atomicAdd(qd + 1, q.y);
                    atomicAdd(qd + 2, q.z); atomicAdd(qd + 3, q.w);
                    if (tq == 0) atomicAdd(cnt + cur, rows);
                    s = (v4f){0.f, 0.f, 0.f, 0.f};
                    q = (v4f){0.f, 0.f, 0.f, 0.f};
                    rows = 0.f;
                }
                cur = seg;
            }
            const v4f a = *reinterpret_cast<const v4f*>(x + (size_t)r * CC + tq * 4);
            s += a; q += a * a;
            rows += 1.f;
        }
        if (cur >= 0) {
            float* sd = sum   + cur * CC + tq * 4;
            float* qd = sumsq + cur * CC + tq * 4;
            atomicAdd(sd + 0, s.x); atomicAdd(sd + 1, s.y);
            atomicAdd(sd + 2, s.z); atomicAdd(sd + 3, s.w);
            atomicAdd(qd + 0, q.x); atomicAdd(qd + 1, q.y);
            atomicAdd(qd + 2, q.z); atomicAdd(qd + 3, q.w);
            if (tq == 0) atomicAdd(cnt + cur, rows);
        }
    }
}

// ---------------------------------------------------------------------------
// Kernel 2: normalize, no LDS. Work unit = "pair" = 2 consecutive float4
// = 32B = 8 channels; 16 pairs per row. Block k owns the k-th contiguous
// chunk FROM THE TAIL of x (the tail was streamed into L3 most recently by
// ms_stats -> mostly L3 hits), iterating its chunk in descending block-steps.
// A thread's channel-octet (p & 15) is invariant (steps of 256), and its rows
// descend contiguously -> scale/shift live in 16 registers, recomputed from
// the L2-hot sum/sumsq tables only on segment change (<=2 times per thread).
// Output uses nontemporal stores so 512 MB of writes don't evict x from L3.
// ---------------------------------------------------------------------------
__global__ __launch_bounds__(256) void ms_norm(const float* __restrict__ x,
                                               const int* __restrict__ bidx,
                                               const float* __restrict__ sum,
                                               const float* __restrict__ sumsq,
                                               const float* __restrict__ cnt,
                                               const float* __restrict__ w,
                                               const float* __restrict__ bias,
                                               float* __restrict__ out,
                                               int n)
{
    const int npairs = n * 16;                               // 16M < 2^31
    const int chunk  = (npairs + (int)gridDim.x - 1) / (int)gridDim.x;
    const int hi     = npairs - (int)blockIdx.x * chunk;     // block 0 -> tail
    if (hi <= 0) return;
    const int lo     = max(hi - chunk, 0);
    const int tid    = (int)threadIdx.x;

    // Fixed channel octet for this thread (256 ≡ 0 mod 16).
    const int c0 = ((hi + tid) & 15) * 8;
    const v4f w0 = *reinterpret_cast<const v4f*>(w + c0);
    const v4f w1 = *reinterpret_cast<const v4f*>(w + c0 + 4);
    const v4f b0 = *reinterpret_cast<const v4f*>(bias + c0);
    const v4f b1 = *reinterpret_cast<const v4f*>(bias + c0 + 4);

    int cur = -1;
    v4f sc0, sc1, sh0, sh1;

    for (int p = hi - 256 + tid; p >= lo; p -= 256) {
        const int r   = p >> 4;
        const int seg = bidx[r];
        if (seg != cur) {
            cur = seg;
            const int gi  = seg * CC + c0;
            const v4f su0 = *reinterpret_cast<const v4f*>(sum + gi);
            const v4f su1 = *reinterpret_cast<const v4f*>(sum + gi + 4);
            const v4f sq0 = *reinterpret_cast<const v4f*>(sumsq + gi);
            const v4f sq1 = *reinterpret_cast<const v4f*>(sumsq + gi + 4);
            const float rn = 1.0f / fmaxf(cnt[seg], 1.0f);
            const v4f m0 = su0 * rn;
            const v4f m1 = su1 * rn;
            const v4f is0 = vrsqrt_eps(vmax0(sq0 * rn - m0 * m0));
            const v4f is1 = vrsqrt_eps(vmax0(sq1 * rn - m1 * m1));
            sc0 = is0 * w0; sc1 = is1 * w1;
            sh0 = b0 - m0 * sc0; sh1 = b1 - m1 * sc1;
        }
        const float* px = x + (size_t)p * 8;
        const v4f a = *reinterpret_cast<const v4f*>(px);
        const v4f b = *reinterpret_cast<const v4f*>(px + 4);
        v4f o0, o1;
        o0.x = fmaf(a.x, sc0.x, sh0.x); o0.y = fmaf(a.y, sc0.y, sh0.y);
        o0.z = fmaf(a.z, sc0.z, sh0.z); o0.w = fmaf(a.w, sc0.w, sh0.w);
        o1.x = fmaf(b.x, sc1.x, sh1.x); o1.y = fmaf(b.y, sc1.y, sh1.y);
        o1.z = fmaf(b.z, sc1.z, sh1.z); o1.w = fmaf(b.w, sc1.w, sh1.w);
        float* po = out + (size_t)p * 8;
        __builtin_nontemporal_store(o0, reinterpret_cast<v4f*>(po));
        __builtin_nontemporal_store(o1, reinterpret_cast<v4f*>(po + 4));
    }
}

// ---------------------------------------------------------------------------
extern "C" void kernel_launch(void* const* d_in, const int* in_sizes, int n_in,
                              void* d_out, int out_size, void* d_ws, size_t ws_size,
                              hipStream_t stream)
{
    const float* x    = (const float*)d_in[0];
    const int*   bidx = (const int*)d_in[1];
    const float* w    = (const float*)d_in[2];
    const float* bias = (const float*)d_in[3];
    float* out = (float*)d_out;
    const int n = in_sizes[1];   // number of rows (batch_idx length)

    // Workspace layout (floats): sum[B*C] | sumsq[B*C] | cnt[B]
    float* ws    = (float*)d_ws;
    float* sum   = ws;
    float* sumsq = ws + BSEG * CC;
    float* cnt   = ws + 2 * BSEG * CC;

    // Zero the accumulators (ws is poisoned; must be replay-safe).
    (void)hipMemsetAsync(d_ws, 0, (size_t)(2 * BSEG * CC + BSEG) * sizeof(float), stream);

    const int g1 = (n + ROWS_PER_BLOCK - 1) / ROWS_PER_BLOCK;
    ms_stats<<<g1, 256, 0, stream>>>(x, bidx, n, sum, sumsq, cnt);
    ms_norm<<<NORM_GRID, 256, 0, stream>>>(x, bidx, sum, sumsq, cnt, w, bias, out, n);
}